// Round 1
// baseline (1380.383 us; speedup 1.0000x reference)
//
#include <hip/hip_runtime.h>
#include <math.h>

#define B_   2
#define S_   2048
#define D_   1024
#define H_   16
#define K_   21
#define HD_  64
#define D3_  3072
#define D2_  2048
#define REL_ 4095  // 2S-1

// ---------------- TISA relative-position bias table ----------------
// bias_rel[h][r] = sum_k amp[h,k] * exp(-|sharp[h,k]| * (rel - off[h,k])^2),
// rel = r - (S-1), r in [0, 2S-2]
__global__ void tisa_bias_kernel(const float* __restrict__ amp,
                                 const float* __restrict__ shp,
                                 const float* __restrict__ off,
                                 float* __restrict__ bias_rel) {
    int idx = blockIdx.x * blockDim.x + threadIdx.x;
    if (idx >= H_ * REL_) return;
    int h = idx / REL_;
    int r = idx - h * REL_;
    float rel = (float)(r - (S_ - 1));
    float acc = 0.f;
    #pragma unroll
    for (int k = 0; k < K_; ++k) {
        float d = rel - off[h * K_ + k];
        acc = fmaf(amp[h * K_ + k], expf(-fabsf(shp[h * K_ + k]) * d * d), acc);
    }
    bias_rel[idx] = acc;
}

// ---------------- fp32 tiled GEMM: C = A(MxK) * B(KxN) [+ bias] ----------------
// 128x128 tile, BK=16, 256 threads, 8x8 micro-tile per thread.
__global__ __launch_bounds__(256) void gemm_bias_kernel(
    const float* __restrict__ A, const float* __restrict__ Bm,
    const float* __restrict__ bias, float* __restrict__ C,
    int M, int N, int Kd)
{
    __shared__ float As[16][132];  // [k][m], transposed on store
    __shared__ float Bs[16][132];  // [k][n]
    const int tid = threadIdx.x;
    const int tx = tid & 15;
    const int ty = tid >> 4;
    const int m0 = blockIdx.y * 128;
    const int n0 = blockIdx.x * 128;

    float acc[8][8];
    #pragma unroll
    for (int i = 0; i < 8; ++i)
        #pragma unroll
        for (int j = 0; j < 8; ++j) acc[i][j] = 0.f;

    const int arow = tid >> 2;         // 0..63
    const int akq  = (tid & 3) << 2;   // 0,4,8,12
    const int bkk  = tid >> 4;         // 0..15
    const int bnc  = (tid & 15) << 3;  // 0..120

    for (int k0 = 0; k0 < Kd; k0 += 16) {
        #pragma unroll
        for (int l = 0; l < 2; ++l) {
            const int row = arow + l * 64;
            const float4 av = *(const float4*)&A[(size_t)(m0 + row) * Kd + k0 + akq];
            As[akq + 0][row] = av.x;
            As[akq + 1][row] = av.y;
            As[akq + 2][row] = av.z;
            As[akq + 3][row] = av.w;
        }
        {
            const float* bp = &Bm[(size_t)(k0 + bkk) * N + n0 + bnc];
            *(float4*)&Bs[bkk][bnc]     = *(const float4*)bp;
            *(float4*)&Bs[bkk][bnc + 4] = *(const float4*)(bp + 4);
        }
        __syncthreads();
        #pragma unroll
        for (int kk = 0; kk < 16; ++kk) {
            float a[8], b[8];
            *(float4*)&a[0] = *(const float4*)&As[kk][ty * 8];
            *(float4*)&a[4] = *(const float4*)&As[kk][ty * 8 + 4];
            *(float4*)&b[0] = *(const float4*)&Bs[kk][tx * 8];
            *(float4*)&b[4] = *(const float4*)&Bs[kk][tx * 8 + 4];
            #pragma unroll
            for (int i = 0; i < 8; ++i)
                #pragma unroll
                for (int j = 0; j < 8; ++j)
                    acc[i][j] = fmaf(a[i], b[j], acc[i][j]);
        }
        __syncthreads();
    }

    #pragma unroll
    for (int i = 0; i < 8; ++i) {
        const int row = m0 + ty * 8 + i;
        float* cp = &C[(size_t)row * N + n0 + tx * 8];
        float o[8];
        #pragma unroll
        for (int j = 0; j < 8; ++j) o[j] = acc[i][j];
        if (bias != nullptr) {
            #pragma unroll
            for (int j = 0; j < 8; ++j) o[j] += bias[n0 + tx * 8 + j];
        }
        *(float4*)cp       = *(float4*)&o[0];
        *(float4*)(cp + 4) = *(float4*)&o[4];
    }
}

// ---------------- flash-style attention, fp32 ----------------
// proj layout per row (3072): [K | V | Q], head h at col h*64 within each third.
// Block = (qtile of 32 rows) x (head) x (batch); 256 threads as 16x16;
// thread (ty,tx) owns score micro-tile rows ty*2..+1, cols tx*4..+3.
__global__ __launch_bounds__(256) void attn_kernel(
    const float* __restrict__ proj, const float* __restrict__ bias_rel,
    float* __restrict__ outp)
{
    __shared__ float Qs[32][68];
    __shared__ float Ks[64][68];
    __shared__ float Vs[64][68];
    __shared__ float Ps[32][68];
    __shared__ float bias_s[96];

    const int tid = threadIdx.x;
    const int tx = tid & 15;
    const int ty = tid >> 4;
    const int qt = blockIdx.x;
    const int h  = blockIdx.y;
    const int b  = blockIdx.z;
    const int qbase = qt * 32;
    const size_t rowbase = (size_t)b * S_;

    // load Q tile (32x64): 2 float4 per thread
    {
        const int r = tid >> 3;
        const int c = (tid & 7) * 8;
        const float* p = proj + (rowbase + qbase + r) * D3_ + 2 * D_ + h * HD_ + c;
        *(float4*)&Qs[r][c]     = *(const float4*)p;
        *(float4*)&Qs[r][c + 4] = *(const float4*)(p + 4);
    }

    float m_run[2] = {-INFINITY, -INFINITY};
    float l_run[2] = {0.f, 0.f};
    float o[2][4] = {{0.f, 0.f, 0.f, 0.f}, {0.f, 0.f, 0.f, 0.f}};

    const int r0 = ty * 2;
    const int c0 = tx * 4;

    for (int kt = 0; kt < S_ / 64; ++kt) {
        const int kbase = kt * 64;
        __syncthreads();  // previous iteration's LDS reads complete
        // stage K and V tiles (64x64 each): 4 float4 pairs per thread
        {
            const int r  = tid >> 2;
            const int cc = (tid & 3) * 16;
            const float* kp = proj + (rowbase + kbase + r) * D3_ + h * HD_ + cc;
            const float* vp = kp + D_;
            #pragma unroll
            for (int q = 0; q < 4; ++q) {
                *(float4*)&Ks[r][cc + q * 4] = *(const float4*)(kp + q * 4);
                *(float4*)&Vs[r][cc + q * 4] = *(const float4*)(vp + q * 4);
            }
        }
        // stage the 95 needed bias entries: diff = (kcol - qrow) in [-31,63]
        if (tid < 96) {
            int idx = kbase - qbase + (S_ - 1) - 31 + tid;
            idx = idx < 0 ? 0 : (idx > REL_ - 1 ? REL_ - 1 : idx);
            bias_s[tid] = bias_rel[h * REL_ + idx];
        }
        __syncthreads();

        // S = Q K^T
        float s[2][4];
        #pragma unroll
        for (int i = 0; i < 2; ++i)
            #pragma unroll
            for (int j = 0; j < 4; ++j) s[i][j] = 0.f;

        #pragma unroll
        for (int d4 = 0; d4 < HD_; d4 += 4) {
            float a[2][4], bb[4][4];
            *(float4*)&a[0][0] = *(const float4*)&Qs[r0 + 0][d4];
            *(float4*)&a[1][0] = *(const float4*)&Qs[r0 + 1][d4];
            #pragma unroll
            for (int j = 0; j < 4; ++j)
                *(float4*)&bb[j][0] = *(const float4*)&Ks[c0 + j][d4];
            #pragma unroll
            for (int i = 0; i < 2; ++i)
                #pragma unroll
                for (int j = 0; j < 4; ++j)
                    #pragma unroll
                    for (int dd = 0; dd < 4; ++dd)
                        s[i][j] = fmaf(a[i][dd], bb[j][dd], s[i][j]);
        }

        // scale + TISA bias
        #pragma unroll
        for (int i = 0; i < 2; ++i)
            #pragma unroll
            for (int j = 0; j < 4; ++j)
                s[i][j] = fmaf(s[i][j], 0.125f, bias_s[(c0 + j) - (r0 + i) + 31]);

        // online softmax (row reduce across the 16 tx lanes)
        #pragma unroll
        for (int i = 0; i < 2; ++i) {
            float mt = fmaxf(fmaxf(s[i][0], s[i][1]), fmaxf(s[i][2], s[i][3]));
            #pragma unroll
            for (int mask = 1; mask < 16; mask <<= 1)
                mt = fmaxf(mt, __shfl_xor(mt, mask, 64));
            const float m_new = fmaxf(m_run[i], mt);
            const float scale = __expf(m_run[i] - m_new);  // 0 on first tile
            float rs = 0.f;
            #pragma unroll
            for (int j = 0; j < 4; ++j) {
                s[i][j] = __expf(s[i][j] - m_new);
                rs += s[i][j];
            }
            #pragma unroll
            for (int mask = 1; mask < 16; mask <<= 1)
                rs += __shfl_xor(rs, mask, 64);
            l_run[i] = l_run[i] * scale + rs;
            m_run[i] = m_new;
            #pragma unroll
            for (int j = 0; j < 4; ++j) o[i][j] *= scale;
            *(float4*)&Ps[r0 + i][c0] = *(float4*)&s[i][0];
        }
        __syncthreads();

        // O += P V
        #pragma unroll
        for (int k4 = 0; k4 < 64; k4 += 4) {
            float p0[4], p1[4];
            *(float4*)&p0[0] = *(const float4*)&Ps[r0 + 0][k4];
            *(float4*)&p1[0] = *(const float4*)&Ps[r0 + 1][k4];
            #pragma unroll
            for (int kk = 0; kk < 4; ++kk) {
                float v[4];
                *(float4*)&v[0] = *(const float4*)&Vs[k4 + kk][c0];
                #pragma unroll
                for (int j = 0; j < 4; ++j) {
                    o[0][j] = fmaf(p0[kk], v[j], o[0][j]);
                    o[1][j] = fmaf(p1[kk], v[j], o[1][j]);
                }
            }
        }
    }

    // normalize and write (heads recombined: out is (B*S, D) row-major)
    #pragma unroll
    for (int i = 0; i < 2; ++i) {
        const float inv = 1.f / l_run[i];
        float v[4];
        #pragma unroll
        for (int j = 0; j < 4; ++j) v[j] = o[i][j] * inv;
        float* op = outp + (rowbase + qbase + r0 + i) * D_ + h * HD_ + c0;
        *(float4*)op = *(float4*)&v[0];
    }
}

// ---------------- gating epilogue: out = a * sigmoid(g) ----------------
__global__ void gate_kernel(const float* __restrict__ gated,
                            float* __restrict__ outp, int n4)
{
    int idx = blockIdx.x * blockDim.x + threadIdx.x;
    const int stride = gridDim.x * blockDim.x;
    for (; idx < n4; idx += stride) {
        const int row = idx >> 8;          // 256 float4 per output row (D=1024)
        const int c   = (idx & 255) * 4;
        const float4 a = *(const float4*)&gated[(size_t)row * D2_ + c];
        const float4 g = *(const float4*)&gated[(size_t)row * D2_ + D_ + c];
        float4 r;
        r.x = a.x / (1.f + __expf(-g.x));
        r.y = a.y / (1.f + __expf(-g.y));
        r.z = a.z / (1.f + __expf(-g.z));
        r.w = a.w / (1.f + __expf(-g.w));
        *(float4*)&outp[(size_t)idx * 4] = r;
    }
}

extern "C" void kernel_launch(void* const* d_in, const int* in_sizes, int n_in,
                              void* d_out, int out_size, void* d_ws, size_t ws_size,
                              hipStream_t stream) {
    const float* x      = (const float*)d_in[0];
    const float* w_in   = (const float*)d_in[1];
    const float* w_gate = (const float*)d_in[2];
    const float* b_gate = (const float*)d_in[3];
    const float* amp    = (const float*)d_in[4];
    const float* shp    = (const float*)d_in[5];
    const float* off    = (const float*)d_in[6];
    float* outp = (float*)d_out;

    char* ws = (char*)d_ws;
    float* proj     = (float*)ws;                                   // 4096x3072 fp32 (48 MB)
    float* attn     = (float*)(ws + (size_t)4096 * 3072 * 4);       // 4096x1024 fp32 (16 MB)
    float* bias_rel = (float*)(ws + (size_t)4096 * 3072 * 4
                                  + (size_t)4096 * 1024 * 4);       // 16x4095 fp32 (256 KB)
    float* gated    = proj;  // proj dead after attention; reuse for 4096x2048 gated

    // 1) TISA bias table
    tisa_bias_kernel<<<(H_ * REL_ + 255) / 256, 256, 0, stream>>>(amp, shp, off, bias_rel);
    // 2) proj = x @ w_in  (M=4096, N=3072, K=1024)
    gemm_bias_kernel<<<dim3(D3_ / 128, (B_ * S_) / 128), 256, 0, stream>>>(
        x, w_in, nullptr, proj, B_ * S_, D3_, D_);
    // 3) attention
    attn_kernel<<<dim3(S_ / 32, H_, B_), 256, 0, stream>>>(proj, bias_rel, attn);
    // 4) gated = attn @ w_gate + b_gate  (M=4096, N=2048, K=1024)
    gemm_bias_kernel<<<dim3(D2_ / 128, (B_ * S_) / 128), 256, 0, stream>>>(
        attn, w_gate, b_gate, gated, B_ * S_, D2_, D_);
    // 5) out = a * sigmoid(g)
    gate_kernel<<<2048, 256, 0, stream>>>(gated, outp, (B_ * S_ * D_) / 4);
}

// Round 2
// 786.679 us; speedup vs baseline: 1.7547x; 1.7547x over previous
//
#include <hip/hip_runtime.h>
#include <math.h>

#define B_   2
#define S_   2048
#define D_   1024
#define H_   16
#define K_   21
#define HD_  64
#define D3_  3072
#define D2_  2048
#define REL_ 4095  // 2S-1

typedef __attribute__((ext_vector_type(8))) short bf16x8;
typedef __attribute__((ext_vector_type(4))) float f32x4;

#define MFMA16(a, b, c) __builtin_amdgcn_mfma_f32_16x16x32_bf16((a), (b), (c), 0, 0, 0)

__device__ __forceinline__ unsigned short f2bf(float f) {
    union { float f; unsigned u; } v; v.f = f;
    return (unsigned short)((v.u + 0x7fffu + ((v.u >> 16) & 1u)) >> 16);
}
__device__ __forceinline__ float bf2f(unsigned short h) {
    union { unsigned u; float f; } v; v.u = ((unsigned)h) << 16;
    return v.f;
}

// ---------------- TISA relative-position bias table ----------------
__global__ void tisa_bias_kernel(const float* __restrict__ amp,
                                 const float* __restrict__ shp,
                                 const float* __restrict__ off,
                                 float* __restrict__ bias_rel) {
    int idx = blockIdx.x * blockDim.x + threadIdx.x;
    if (idx >= H_ * REL_) return;
    int h = idx / REL_;
    int r = idx - h * REL_;
    float rel = (float)(r - (S_ - 1));
    float acc = 0.f;
    #pragma unroll
    for (int k = 0; k < K_; ++k) {
        float d = rel - off[h * K_ + k];
        acc = fmaf(amp[h * K_ + k], expf(-fabsf(shp[h * K_ + k]) * d * d), acc);
    }
    bias_rel[idx] = acc;
}

// ---------------- fp32 tiled GEMM: C = A(MxK) * B(KxN) [+ bias] ----------------
__global__ __launch_bounds__(256) void gemm_bias_kernel(
    const float* __restrict__ A, const float* __restrict__ Bm,
    const float* __restrict__ bias, float* __restrict__ C,
    int M, int N, int Kd)
{
    __shared__ float As[16][132];
    __shared__ float Bs[16][132];
    const int tid = threadIdx.x;
    const int tx = tid & 15;
    const int ty = tid >> 4;
    const int m0 = blockIdx.y * 128;
    const int n0 = blockIdx.x * 128;

    float acc[8][8];
    #pragma unroll
    for (int i = 0; i < 8; ++i)
        #pragma unroll
        for (int j = 0; j < 8; ++j) acc[i][j] = 0.f;

    const int arow = tid >> 2;
    const int akq  = (tid & 3) << 2;
    const int bkk  = tid >> 4;
    const int bnc  = (tid & 15) << 3;

    for (int k0 = 0; k0 < Kd; k0 += 16) {
        #pragma unroll
        for (int l = 0; l < 2; ++l) {
            const int row = arow + l * 64;
            const float4 av = *(const float4*)&A[(size_t)(m0 + row) * Kd + k0 + akq];
            As[akq + 0][row] = av.x;
            As[akq + 1][row] = av.y;
            As[akq + 2][row] = av.z;
            As[akq + 3][row] = av.w;
        }
        {
            const float* bp = &Bm[(size_t)(k0 + bkk) * N + n0 + bnc];
            *(float4*)&Bs[bkk][bnc]     = *(const float4*)bp;
            *(float4*)&Bs[bkk][bnc + 4] = *(const float4*)(bp + 4);
        }
        __syncthreads();
        #pragma unroll
        for (int kk = 0; kk < 16; ++kk) {
            float a[8], b[8];
            *(float4*)&a[0] = *(const float4*)&As[kk][ty * 8];
            *(float4*)&a[4] = *(const float4*)&As[kk][ty * 8 + 4];
            *(float4*)&b[0] = *(const float4*)&Bs[kk][tx * 8];
            *(float4*)&b[4] = *(const float4*)&Bs[kk][tx * 8 + 4];
            #pragma unroll
            for (int i = 0; i < 8; ++i)
                #pragma unroll
                for (int j = 0; j < 8; ++j)
                    acc[i][j] = fmaf(a[i], b[j], acc[i][j]);
        }
        __syncthreads();
    }

    #pragma unroll
    for (int i = 0; i < 8; ++i) {
        const int row = m0 + ty * 8 + i;
        float* cp = &C[(size_t)row * N + n0 + tx * 8];
        float o[8];
        #pragma unroll
        for (int j = 0; j < 8; ++j) o[j] = acc[i][j];
        if (bias != nullptr) {
            #pragma unroll
            for (int j = 0; j < 8; ++j) o[j] += bias[n0 + tx * 8 + j];
        }
        *(float4*)cp       = *(float4*)&o[0];
        *(float4*)(cp + 4) = *(float4*)&o[4];
    }
}

// ---------------- MFMA flash attention, bf16x3 split precision ----------------
// proj row layout (3072): [K | V | Q]; head h at col h*64 within each third.
// Block: 256 thr = 4 waves; 64 q-rows/block (16/wave); KV tile = 64.
// mfma_f32_16x16x32_bf16; A-frag: lane holds row l%16, k=(l/16)*8+j;
// B-frag: lane holds col l%16, k=(l/16)*8+j; D: lane holds col l%16, row=(l/16)*4+r.
__global__ __launch_bounds__(256) void attn_mfma_kernel(
    const float* __restrict__ proj, const float* __restrict__ bias_rel,
    float* __restrict__ outp)
{
    __shared__ unsigned short Khi[64 * 64], Klo[64 * 64];   // [k][d], swizzled
    __shared__ unsigned short Vthi[64 * 64], Vtlo[64 * 64]; // [d][k], swizzled
    __shared__ unsigned P32[64 * 64];                       // [q_blk][k], hi|lo<<16
    __shared__ float bias_s[128];

    const int tid  = threadIdx.x;
    const int w    = tid >> 6;
    const int lane = tid & 63;
    const int c    = lane & 15;   // fragment column
    const int g    = lane >> 4;   // lane group
    const int qt   = blockIdx.x;
    const int h    = blockIdx.y;
    const int b    = blockIdx.z;
    const int qbase = qt * 64;
    const size_t rowbase = (size_t)b * S_;

    // Q A-fragments: lane holds Q[qbase+16w+c][ck*32 + g*8 + j], split hi/lo.
    bf16x8 Qhi[2], Qlo[2];
    {
        const float* qp = proj + (rowbase + qbase + 16 * w + c) * D3_ + 2 * D_ + h * HD_;
        #pragma unroll
        for (int ck = 0; ck < 2; ++ck) {
            float q8[8];
            *(float4*)&q8[0] = *(const float4*)(qp + ck * 32 + g * 8);
            *(float4*)&q8[4] = *(const float4*)(qp + ck * 32 + g * 8 + 4);
            #pragma unroll
            for (int j = 0; j < 8; ++j) {
                unsigned short hi = f2bf(q8[j]);
                Qhi[ck][j] = (short)hi;
                Qlo[ck][j] = (short)f2bf(q8[j] - bf2f(hi));
            }
        }
    }

    f32x4 o_acc[4];
    #pragma unroll
    for (int n = 0; n < 4; ++n) o_acc[n] = (f32x4){0.f, 0.f, 0.f, 0.f};
    float m_run[4] = {-INFINITY, -INFINITY, -INFINITY, -INFINITY};
    float l_run[4] = {0.f, 0.f, 0.f, 0.f};

    for (int kt = 0; kt < S_ / 64; ++kt) {
        const int kbase = kt * 64;
        __syncthreads();  // previous tile's LDS reads complete

        // ---- stage K (row-major hi/lo) and V (transposed hi/lo) ----
        {
            const int r   = tid >> 2;
            const int c16 = (tid & 3) * 16;
            const float* kp = proj + (rowbase + kbase + r) * D3_ + h * HD_ + c16;
            const float* vp = kp + D_;
            float kb[16], vb[16];
            #pragma unroll
            for (int e = 0; e < 4; ++e) {
                *(float4*)&kb[4 * e] = *(const float4*)(kp + 4 * e);
                *(float4*)&vb[4 * e] = *(const float4*)(vp + 4 * e);
            }
            #pragma unroll
            for (int e = 0; e < 4; ++e) {
                ushort4 hi4, lo4;
                hi4.x = f2bf(kb[4 * e + 0]); lo4.x = f2bf(kb[4 * e + 0] - bf2f(hi4.x));
                hi4.y = f2bf(kb[4 * e + 1]); lo4.y = f2bf(kb[4 * e + 1] - bf2f(hi4.y));
                hi4.z = f2bf(kb[4 * e + 2]); lo4.z = f2bf(kb[4 * e + 2] - bf2f(hi4.z));
                hi4.w = f2bf(kb[4 * e + 3]); lo4.w = f2bf(kb[4 * e + 3] - bf2f(hi4.w));
                const int idx = (r * 64 + c16 + 4 * e) ^ ((r & 7) << 3);
                *(ushort4*)&Khi[idx] = hi4;
                *(ushort4*)&Klo[idx] = lo4;
            }
            #pragma unroll
            for (int e = 0; e < 16; ++e) {
                const int d = c16 + e;
                const int idx = (d * 64 + r) ^ ((d & 7) << 3) ^ (((d >> 4) & 3) << 4);
                unsigned short hi = f2bf(vb[e]);
                Vthi[idx] = hi;
                Vtlo[idx] = f2bf(vb[e] - bf2f(hi));
            }
        }
        if (tid < 127)
            bias_s[tid] = bias_rel[h * REL_ + kbase - qbase + tid + 1984];
        __syncthreads();

        // ---- S = Q K^T (bf16x3) ----
        f32x4 sf[4];
        #pragma unroll
        for (int f = 0; f < 4; ++f) {
            f32x4 acc = (f32x4){0.f, 0.f, 0.f, 0.f};
            const int krow = f * 16 + c;
            #pragma unroll
            for (int ck = 0; ck < 2; ++ck) {
                const int idx = (krow * 64 + ck * 32 + g * 8) ^ ((krow & 7) << 3);
                bf16x8 kh = *(const bf16x8*)&Khi[idx];
                bf16x8 kl = *(const bf16x8*)&Klo[idx];
                acc = MFMA16(Qhi[ck], kh, acc);
                acc = MFMA16(Qlo[ck], kh, acc);
                acc = MFMA16(Qhi[ck], kl, acc);
            }
            sf[f] = acc;
        }

        // ---- scale + bias ----
        #pragma unroll
        for (int f = 0; f < 4; ++f) {
            const int base = 16 * f + c + 63 - 16 * w - 4 * g;
            #pragma unroll
            for (int r = 0; r < 4; ++r)
                sf[f][r] = fmaf(sf[f][r], 0.125f, bias_s[base - r]);
        }

        // ---- online softmax (row = 4g+r, reduce over 16-lane group) ----
        #pragma unroll
        for (int r = 0; r < 4; ++r) {
            float mt = fmaxf(fmaxf(sf[0][r], sf[1][r]), fmaxf(sf[2][r], sf[3][r]));
            #pragma unroll
            for (int mask = 1; mask < 16; mask <<= 1)
                mt = fmaxf(mt, __shfl_xor(mt, mask));
            const float mn = fmaxf(m_run[r], mt);
            const float sc = __expf(m_run[r] - mn);
            float rs = 0.f;
            #pragma unroll
            for (int f = 0; f < 4; ++f) {
                const float p = __expf(sf[f][r] - mn);
                sf[f][r] = p;
                rs += p;
            }
            #pragma unroll
            for (int mask = 1; mask < 16; mask <<= 1)
                rs += __shfl_xor(rs, mask);
            l_run[r] = l_run[r] * sc + rs;
            m_run[r] = mn;
            #pragma unroll
            for (int n = 0; n < 4; ++n) o_acc[n][r] *= sc;
        }

        // ---- write P to LDS (packed hi|lo<<16, swizzled) ----
        #pragma unroll
        for (int f = 0; f < 4; ++f) {
            #pragma unroll
            for (int r = 0; r < 4; ++r) {
                const int m = 4 * g + r;
                const unsigned short hi = f2bf(sf[f][r]);
                const unsigned short lo = f2bf(sf[f][r] - bf2f(hi));
                P32[((16 * w + m) * 64 + 16 * f + c) ^ ((m & 7) << 2)] =
                    (unsigned)hi | ((unsigned)lo << 16);
            }
        }
        __syncthreads();

        // ---- O += P V (bf16x3) ----
        #pragma unroll
        for (int ck = 0; ck < 2; ++ck) {
            const int base = (16 * w + c) * 64 + ck * 32 + g * 8;
            const int x = (c & 7) << 2;
            uint4 w0 = *(const uint4*)&P32[base ^ x];
            uint4 w1 = *(const uint4*)&P32[(base + 4) ^ x];
            unsigned v[8] = {w0.x, w0.y, w0.z, w0.w, w1.x, w1.y, w1.z, w1.w};
            union { unsigned u[4]; bf16x8 v; } ph, pl;
            #pragma unroll
            for (int j = 0; j < 4; ++j) {
                ph.u[j] = __builtin_amdgcn_perm(v[2 * j + 1], v[2 * j], 0x05040100u);
                pl.u[j] = __builtin_amdgcn_perm(v[2 * j + 1], v[2 * j], 0x07060302u);
            }
            #pragma unroll
            for (int n = 0; n < 4; ++n) {
                const int d = 16 * n + c;
                const int vidx = (d * 64 + ck * 32 + g * 8) ^ ((d & 7) << 3) ^ (((d >> 4) & 3) << 4);
                bf16x8 vh = *(const bf16x8*)&Vthi[vidx];
                bf16x8 vl = *(const bf16x8*)&Vtlo[vidx];
                o_acc[n] = MFMA16(ph.v, vh, o_acc[n]);
                o_acc[n] = MFMA16(pl.v, vh, o_acc[n]);
                o_acc[n] = MFMA16(ph.v, vl, o_acc[n]);
            }
        }
    }

    // ---- normalize + store ----
    #pragma unroll
    for (int r = 0; r < 4; ++r) {
        const float inv = 1.f / l_run[r];
        float* op = outp + (rowbase + qbase + 16 * w + 4 * g + r) * D_ + h * HD_;
        #pragma unroll
        for (int n = 0; n < 4; ++n)
            op[16 * n + c] = o_acc[n][r] * inv;
    }
}

// ---------------- gating epilogue: out = a * sigmoid(g) ----------------
__global__ void gate_kernel(const float* __restrict__ gated,
                            float* __restrict__ outp, int n4)
{
    int idx = blockIdx.x * blockDim.x + threadIdx.x;
    const int stride = gridDim.x * blockDim.x;
    for (; idx < n4; idx += stride) {
        const int row = idx >> 8;
        const int c   = (idx & 255) * 4;
        const float4 a = *(const float4*)&gated[(size_t)row * D2_ + c];
        const float4 g = *(const float4*)&gated[(size_t)row * D2_ + D_ + c];
        float4 r;
        r.x = a.x / (1.f + __expf(-g.x));
        r.y = a.y / (1.f + __expf(-g.y));
        r.z = a.z / (1.f + __expf(-g.z));
        r.w = a.w / (1.f + __expf(-g.w));
        *(float4*)&outp[(size_t)idx * 4] = r;
    }
}

extern "C" void kernel_launch(void* const* d_in, const int* in_sizes, int n_in,
                              void* d_out, int out_size, void* d_ws, size_t ws_size,
                              hipStream_t stream) {
    const float* x      = (const float*)d_in[0];
    const float* w_in   = (const float*)d_in[1];
    const float* w_gate = (const float*)d_in[2];
    const float* b_gate = (const float*)d_in[3];
    const float* amp    = (const float*)d_in[4];
    const float* shp    = (const float*)d_in[5];
    const float* off    = (const float*)d_in[6];
    float* outp = (float*)d_out;

    char* ws = (char*)d_ws;
    float* proj     = (float*)ws;                                   // 4096x3072 fp32
    float* attn     = (float*)(ws + (size_t)4096 * 3072 * 4);       // 4096x1024 fp32
    float* bias_rel = (float*)(ws + (size_t)4096 * 3072 * 4
                                  + (size_t)4096 * 1024 * 4);       // 16x4095 fp32
    float* gated    = proj;  // reuse proj after attention

    tisa_bias_kernel<<<(H_ * REL_ + 255) / 256, 256, 0, stream>>>(amp, shp, off, bias_rel);
    gemm_bias_kernel<<<dim3(D3_ / 128, (B_ * S_) / 128), 256, 0, stream>>>(
        x, w_in, nullptr, proj, B_ * S_, D3_, D_);
    attn_mfma_kernel<<<dim3(S_ / 64, H_, B_), 256, 0, stream>>>(proj, bias_rel, attn);
    gemm_bias_kernel<<<dim3(D2_ / 128, (B_ * S_) / 128), 256, 0, stream>>>(
        attn, w_gate, b_gate, gated, B_ * S_, D2_, D_);
    gate_kernel<<<2048, 256, 0, stream>>>(gated, outp, (B_ * S_ * D_) / 4);
}

// Round 3
// 432.560 us; speedup vs baseline: 3.1912x; 1.8187x over previous
//
#include <hip/hip_runtime.h>
#include <math.h>

#define B_   2
#define S_   2048
#define D_   1024
#define H_   16
#define K_   21
#define HD_  64
#define D3_  3072
#define D2_  2048
#define REL_ 4095  // 2S-1

typedef __attribute__((ext_vector_type(8))) short bf16x8;
typedef __attribute__((ext_vector_type(8))) unsigned short u16x8;
typedef __attribute__((ext_vector_type(4))) float f32x4;

#define MFMA16(a, b, c) __builtin_amdgcn_mfma_f32_16x16x32_bf16((a), (b), (c), 0, 0, 0)

__device__ __forceinline__ unsigned short f2bf(float f) {
    union { float f; unsigned u; } v; v.f = f;
    return (unsigned short)((v.u + 0x7fffu + ((v.u >> 16) & 1u)) >> 16);
}
__device__ __forceinline__ float bf2f(unsigned short h) {
    union { unsigned u; float f; } v; v.u = ((unsigned)h) << 16;
    return v.f;
}

// async global->LDS, 16B per lane; lptr must be the wave-uniform base
__device__ __forceinline__ void gload16(const void* g, void* l) {
    __builtin_amdgcn_global_load_lds(
        (const __attribute__((address_space(1))) unsigned int*)g,
        (__attribute__((address_space(3))) unsigned int*)l, 16, 0, 0);
}

// ---------------- TISA relative-position bias table ----------------
__global__ void tisa_bias_kernel(const float* __restrict__ amp,
                                 const float* __restrict__ shp,
                                 const float* __restrict__ off,
                                 float* __restrict__ bias_rel) {
    int idx = blockIdx.x * blockDim.x + threadIdx.x;
    if (idx >= H_ * REL_) return;
    int h = idx / REL_;
    int r = idx - h * REL_;
    float rel = (float)(r - (S_ - 1));
    float acc = 0.f;
    #pragma unroll
    for (int k = 0; k < K_; ++k) {
        float d = rel - off[h * K_ + k];
        acc = fmaf(amp[h * K_ + k], expf(-fabsf(shp[h * K_ + k]) * d * d), acc);
    }
    bias_rel[idx] = acc;
}

// ---------------- weight transpose + bf16 split ----------------
// in: Kd x N fp32 row-major.  out: [N][Kd/32][64] ushort, chunk = hi[32] | lo[32].
__global__ __launch_bounds__(256) void convert_wT_kernel(
    const float* __restrict__ in, unsigned short* __restrict__ out, int Kd, int N)
{
    __shared__ float t[64][65];
    const int tid = threadIdx.x;
    const int k0 = blockIdx.y * 64;
    const int n0 = blockIdx.x * 64;
    {
        const int r  = tid >> 2;
        const int cq = (tid & 3) * 16;
        #pragma unroll
        for (int e = 0; e < 4; ++e) {
            float4 v = *(const float4*)&in[(size_t)(k0 + r) * N + n0 + cq + 4 * e];
            t[r][cq + 4 * e + 0] = v.x;
            t[r][cq + 4 * e + 1] = v.y;
            t[r][cq + 4 * e + 2] = v.z;
            t[r][cq + 4 * e + 3] = v.w;
        }
    }
    __syncthreads();
    {
        const int n  = tid >> 2;
        const int ks = (tid & 3) * 16;
        const int nkc = Kd >> 5;
        unsigned short hi[16], lo[16];
        #pragma unroll
        for (int i = 0; i < 16; ++i) {
            float v = t[ks + i][n];
            hi[i] = f2bf(v);
            lo[i] = f2bf(v - bf2f(hi[i]));
        }
        const int kg = k0 + ks;
        const int kc = kg >> 5;
        const int j0 = kg & 31;  // 0 or 16
        unsigned short* op = out + (size_t)(n0 + n) * (nkc * 64) + kc * 64;
        *(u16x8*)&op[j0]          = *(u16x8*)&hi[0];
        *(u16x8*)&op[j0 + 8]      = *(u16x8*)&hi[8];
        *(u16x8*)&op[32 + j0]     = *(u16x8*)&lo[0];
        *(u16x8*)&op[32 + j0 + 8] = *(u16x8*)&lo[8];
    }
}

// ---------------- bf16x3 split-precision MFMA GEMM ----------------
// C(MxN fp32) = A(MxK) * B(KxN) [+bias], via hi/lo bf16 split, 3 MFMA terms.
// B pre-converted: [N][K/32][hi32|lo32].  A: fp32 row-major (ASPLIT=false,
// converted in-register during staging) or pre-split like B (ASPLIT=true).
// 128x128 tile, 4 waves (2x2), BK=32; LDS rows 128B, XOR slot swizzle s^(row&7).
template<bool ASPLIT>
__global__ __launch_bounds__(256) void gemm_split_kernel(
    const void* __restrict__ Ap, const unsigned short* __restrict__ Bt,
    const float* __restrict__ bias, float* __restrict__ C,
    int M, int N, int Kd)
{
    __shared__ unsigned short Al[128 * 64];  // 16 KB
    __shared__ unsigned short Bl[128 * 64];  // 16 KB
    const int tid  = threadIdx.x;
    const int w    = tid >> 6;
    const int lane = tid & 63;
    const int c    = lane & 15;
    const int g    = lane >> 4;
    const int m0   = blockIdx.y * 128;
    const int n0   = blockIdx.x * 128;
    const int wrow = (w >> 1) * 64;
    const int wcol = (w & 1) * 64;
    const int nkc  = Kd >> 5;

    f32x4 acc[4][4];
    #pragma unroll
    for (int i = 0; i < 4; ++i)
        #pragma unroll
        for (int j = 0; j < 4; ++j) acc[i][j] = (f32x4){0.f, 0.f, 0.f, 0.f};

    const int srow  = w * 8 + (lane >> 3);  // staging row within 32-row group
    const int sslot = lane & 7;             // staging 16B slot

    for (int kc = 0; kc < nkc; ++kc) {
        // ---- stage A ----
        if (ASPLIT) {
            #pragma unroll
            for (int i = 0; i < 4; ++i) {
                const int m = i * 32 + srow;
                const unsigned short* src = (const unsigned short*)Ap
                    + ((size_t)(m0 + m) * nkc + kc) * 64 + ((sslot ^ (m & 7)) << 3);
                gload16(src, (char*)Al + i * 4096 + w * 1024);
            }
        } else {
            const int am = tid >> 1;
            const int ah_ = tid & 1;
            const float* ap = (const float*)Ap + (size_t)(m0 + am) * Kd + kc * 32 + ah_ * 16;
            float v[16];
            #pragma unroll
            for (int e = 0; e < 4; ++e)
                *(float4*)&v[4 * e] = *(const float4*)(ap + 4 * e);
            unsigned short hi[16], lo[16];
            #pragma unroll
            for (int i = 0; i < 16; ++i) {
                hi[i] = f2bf(v[i]);
                lo[i] = f2bf(v[i] - bf2f(hi[i]));
            }
            const int x = am & 7;
            char* rowp = (char*)Al + am * 128;
            *(u16x8*)(rowp + (((ah_ * 2 + 0) ^ x) << 4)) = *(u16x8*)&hi[0];
            *(u16x8*)(rowp + (((ah_ * 2 + 1) ^ x) << 4)) = *(u16x8*)&hi[8];
            *(u16x8*)(rowp + (((ah_ * 2 + 4) ^ x) << 4)) = *(u16x8*)&lo[0];
            *(u16x8*)(rowp + (((ah_ * 2 + 5) ^ x) << 4)) = *(u16x8*)&lo[8];
        }
        // ---- stage B ----
        #pragma unroll
        for (int i = 0; i < 4; ++i) {
            const int n = i * 32 + srow;
            const unsigned short* src = Bt
                + ((size_t)(n0 + n) * nkc + kc) * 64 + ((sslot ^ (n & 7)) << 3);
            gload16(src, (char*)Bl + i * 4096 + w * 1024);
        }
        __syncthreads();

        // ---- fragments + MFMA ----
        bf16x8 ah[4], al[4], bh[4], bl[4];
        #pragma unroll
        for (int f = 0; f < 4; ++f) {
            const int m = wrow + f * 16 + c;
            const char* rp = (const char*)Al + m * 128;
            ah[f] = *(const bf16x8*)(rp + (((g + 0) ^ (m & 7)) << 4));
            al[f] = *(const bf16x8*)(rp + (((g + 4) ^ (m & 7)) << 4));
            const int n = wcol + f * 16 + c;
            const char* rq = (const char*)Bl + n * 128;
            bh[f] = *(const bf16x8*)(rq + (((g + 0) ^ (n & 7)) << 4));
            bl[f] = *(const bf16x8*)(rq + (((g + 4) ^ (n & 7)) << 4));
        }
        #pragma unroll
        for (int mf = 0; mf < 4; ++mf)
            #pragma unroll
            for (int nf = 0; nf < 4; ++nf) {
                acc[mf][nf] = MFMA16(ah[mf], bh[nf], acc[mf][nf]);
                acc[mf][nf] = MFMA16(al[mf], bh[nf], acc[mf][nf]);
                acc[mf][nf] = MFMA16(ah[mf], bl[nf], acc[mf][nf]);
            }
        __syncthreads();
    }

    // ---- epilogue ----
    float bs[4] = {0.f, 0.f, 0.f, 0.f};
    if (bias != nullptr) {
        #pragma unroll
        for (int nf = 0; nf < 4; ++nf) bs[nf] = bias[n0 + wcol + nf * 16 + c];
    }
    #pragma unroll
    for (int mf = 0; mf < 4; ++mf) {
        #pragma unroll
        for (int r = 0; r < 4; ++r) {
            const int row = m0 + wrow + mf * 16 + g * 4 + r;
            float* cp = &C[(size_t)row * N + n0 + wcol + c];
            #pragma unroll
            for (int nf = 0; nf < 4; ++nf)
                cp[nf * 16] = acc[mf][nf][r] + bs[nf];
        }
    }
}

// ---------------- MFMA flash attention, bf16x3 split precision ----------------
// proj row layout (3072): [K | V | Q]; head h at col h*64 within each third.
// Output written directly in split layout [row][D/32][hi32|lo32] for GEMM2.
__global__ __launch_bounds__(256) void attn_mfma_kernel(
    const float* __restrict__ proj, const float* __restrict__ bias_rel,
    unsigned short* __restrict__ asplit)
{
    __shared__ unsigned short Khi[64 * 64], Klo[64 * 64];   // [k][d], swizzled
    __shared__ unsigned short Vthi[64 * 64], Vtlo[64 * 64]; // [d][k], swizzled
    __shared__ unsigned P32[64 * 64];                       // [q_blk][k], hi|lo<<16
    __shared__ float bias_s[128];

    const int tid  = threadIdx.x;
    const int w    = tid >> 6;
    const int lane = tid & 63;
    const int c    = lane & 15;
    const int g    = lane >> 4;
    const int qt   = blockIdx.x;
    const int h    = blockIdx.y;
    const int b    = blockIdx.z;
    const int qbase = qt * 64;
    const size_t rowbase = (size_t)b * S_;

    bf16x8 Qhi[2], Qlo[2];
    {
        const float* qp = proj + (rowbase + qbase + 16 * w + c) * D3_ + 2 * D_ + h * HD_;
        #pragma unroll
        for (int ck = 0; ck < 2; ++ck) {
            float q8[8];
            *(float4*)&q8[0] = *(const float4*)(qp + ck * 32 + g * 8);
            *(float4*)&q8[4] = *(const float4*)(qp + ck * 32 + g * 8 + 4);
            #pragma unroll
            for (int j = 0; j < 8; ++j) {
                unsigned short hi = f2bf(q8[j]);
                Qhi[ck][j] = (short)hi;
                Qlo[ck][j] = (short)f2bf(q8[j] - bf2f(hi));
            }
        }
    }

    f32x4 o_acc[4];
    #pragma unroll
    for (int n = 0; n < 4; ++n) o_acc[n] = (f32x4){0.f, 0.f, 0.f, 0.f};
    float m_run[4] = {-INFINITY, -INFINITY, -INFINITY, -INFINITY};
    float l_run[4] = {0.f, 0.f, 0.f, 0.f};

    for (int kt = 0; kt < S_ / 64; ++kt) {
        const int kbase = kt * 64;
        __syncthreads();

        {
            const int r   = tid >> 2;
            const int c16 = (tid & 3) * 16;
            const float* kp = proj + (rowbase + kbase + r) * D3_ + h * HD_ + c16;
            const float* vp = kp + D_;
            float kb[16], vb[16];
            #pragma unroll
            for (int e = 0; e < 4; ++e) {
                *(float4*)&kb[4 * e] = *(const float4*)(kp + 4 * e);
                *(float4*)&vb[4 * e] = *(const float4*)(vp + 4 * e);
            }
            #pragma unroll
            for (int e = 0; e < 4; ++e) {
                ushort4 hi4, lo4;
                hi4.x = f2bf(kb[4 * e + 0]); lo4.x = f2bf(kb[4 * e + 0] - bf2f(hi4.x));
                hi4.y = f2bf(kb[4 * e + 1]); lo4.y = f2bf(kb[4 * e + 1] - bf2f(hi4.y));
                hi4.z = f2bf(kb[4 * e + 2]); lo4.z = f2bf(kb[4 * e + 2] - bf2f(hi4.z));
                hi4.w = f2bf(kb[4 * e + 3]); lo4.w = f2bf(kb[4 * e + 3] - bf2f(hi4.w));
                const int idx = (r * 64 + c16 + 4 * e) ^ ((r & 7) << 3);
                *(ushort4*)&Khi[idx] = hi4;
                *(ushort4*)&Klo[idx] = lo4;
            }
            #pragma unroll
            for (int e = 0; e < 16; ++e) {
                const int d = c16 + e;
                const int idx = (d * 64 + r) ^ ((d & 7) << 3) ^ (((d >> 4) & 3) << 4);
                unsigned short hi = f2bf(vb[e]);
                Vthi[idx] = hi;
                Vtlo[idx] = f2bf(vb[e] - bf2f(hi));
            }
        }
        if (tid < 127)
            bias_s[tid] = bias_rel[h * REL_ + kbase - qbase + tid + 1984];
        __syncthreads();

        f32x4 sf[4];
        #pragma unroll
        for (int f = 0; f < 4; ++f) {
            f32x4 acc = (f32x4){0.f, 0.f, 0.f, 0.f};
            const int krow = f * 16 + c;
            #pragma unroll
            for (int ck = 0; ck < 2; ++ck) {
                const int idx = (krow * 64 + ck * 32 + g * 8) ^ ((krow & 7) << 3);
                bf16x8 kh = *(const bf16x8*)&Khi[idx];
                bf16x8 kl = *(const bf16x8*)&Klo[idx];
                acc = MFMA16(Qhi[ck], kh, acc);
                acc = MFMA16(Qlo[ck], kh, acc);
                acc = MFMA16(Qhi[ck], kl, acc);
            }
            sf[f] = acc;
        }

        #pragma unroll
        for (int f = 0; f < 4; ++f) {
            const int base = 16 * f + c + 63 - 16 * w - 4 * g;
            #pragma unroll
            for (int r = 0; r < 4; ++r)
                sf[f][r] = fmaf(sf[f][r], 0.125f, bias_s[base - r]);
        }

        #pragma unroll
        for (int r = 0; r < 4; ++r) {
            float mt = fmaxf(fmaxf(sf[0][r], sf[1][r]), fmaxf(sf[2][r], sf[3][r]));
            #pragma unroll
            for (int mask = 1; mask < 16; mask <<= 1)
                mt = fmaxf(mt, __shfl_xor(mt, mask));
            const float mn = fmaxf(m_run[r], mt);
            const float sc = __expf(m_run[r] - mn);
            float rs = 0.f;
            #pragma unroll
            for (int f = 0; f < 4; ++f) {
                const float p = __expf(sf[f][r] - mn);
                sf[f][r] = p;
                rs += p;
            }
            #pragma unroll
            for (int mask = 1; mask < 16; mask <<= 1)
                rs += __shfl_xor(rs, mask);
            l_run[r] = l_run[r] * sc + rs;
            m_run[r] = mn;
            #pragma unroll
            for (int n = 0; n < 4; ++n) o_acc[n][r] *= sc;
        }

        #pragma unroll
        for (int f = 0; f < 4; ++f) {
            #pragma unroll
            for (int r = 0; r < 4; ++r) {
                const int m = 4 * g + r;
                const unsigned short hi = f2bf(sf[f][r]);
                const unsigned short lo = f2bf(sf[f][r] - bf2f(hi));
                P32[((16 * w + m) * 64 + 16 * f + c) ^ ((m & 7) << 2)] =
                    (unsigned)hi | ((unsigned)lo << 16);
            }
        }
        __syncthreads();

        #pragma unroll
        for (int ck = 0; ck < 2; ++ck) {
            const int base = (16 * w + c) * 64 + ck * 32 + g * 8;
            const int x = (c & 7) << 2;
            uint4 w0 = *(const uint4*)&P32[base ^ x];
            uint4 w1 = *(const uint4*)&P32[(base + 4) ^ x];
            unsigned v[8] = {w0.x, w0.y, w0.z, w0.w, w1.x, w1.y, w1.z, w1.w};
            union { unsigned u[4]; bf16x8 v; } ph, pl;
            #pragma unroll
            for (int j = 0; j < 4; ++j) {
                ph.u[j] = __builtin_amdgcn_perm(v[2 * j + 1], v[2 * j], 0x05040100u);
                pl.u[j] = __builtin_amdgcn_perm(v[2 * j + 1], v[2 * j], 0x07060302u);
            }
            #pragma unroll
            for (int n = 0; n < 4; ++n) {
                const int d = 16 * n + c;
                const int vidx = (d * 64 + ck * 32 + g * 8) ^ ((d & 7) << 3) ^ (((d >> 4) & 3) << 4);
                bf16x8 vh = *(const bf16x8*)&Vthi[vidx];
                bf16x8 vl = *(const bf16x8*)&Vtlo[vidx];
                o_acc[n] = MFMA16(ph.v, vh, o_acc[n]);
                o_acc[n] = MFMA16(pl.v, vh, o_acc[n]);
                o_acc[n] = MFMA16(ph.v, vl, o_acc[n]);
            }
        }
    }

    // ---- normalize + store in split layout [row][32 chunks][hi32|lo32] ----
    #pragma unroll
    for (int r = 0; r < 4; ++r) {
        const float inv = 1.f / l_run[r];
        unsigned short* op = asplit + (rowbase + qbase + 16 * w + 4 * g + r) * (size_t)2048;
        #pragma unroll
        for (int n = 0; n < 4; ++n) {
            const float v = o_acc[n][r] * inv;
            const int col = h * HD_ + 16 * n + c;
            const int kc = col >> 5;
            const int j  = col & 31;
            const unsigned short hi = f2bf(v);
            op[kc * 64 + j]      = hi;
            op[kc * 64 + 32 + j] = f2bf(v - bf2f(hi));
        }
    }
}

// ---------------- gating epilogue: out = a * sigmoid(g) ----------------
__global__ void gate_kernel(const float* __restrict__ gated,
                            float* __restrict__ outp, int n4)
{
    int idx = blockIdx.x * blockDim.x + threadIdx.x;
    const int stride = gridDim.x * blockDim.x;
    for (; idx < n4; idx += stride) {
        const int row = idx >> 8;
        const int c   = (idx & 255) * 4;
        const float4 a = *(const float4*)&gated[(size_t)row * D2_ + c];
        const float4 g = *(const float4*)&gated[(size_t)row * D2_ + D_ + c];
        float4 r;
        r.x = a.x / (1.f + __expf(-g.x));
        r.y = a.y / (1.f + __expf(-g.y));
        r.z = a.z / (1.f + __expf(-g.z));
        r.w = a.w / (1.f + __expf(-g.w));
        *(float4*)&outp[(size_t)idx * 4] = r;
    }
}

extern "C" void kernel_launch(void* const* d_in, const int* in_sizes, int n_in,
                              void* d_out, int out_size, void* d_ws, size_t ws_size,
                              hipStream_t stream) {
    const float* x      = (const float*)d_in[0];
    const float* w_in   = (const float*)d_in[1];
    const float* w_gate = (const float*)d_in[2];
    const float* b_gate = (const float*)d_in[3];
    const float* amp    = (const float*)d_in[4];
    const float* shp    = (const float*)d_in[5];
    const float* off    = (const float*)d_in[6];
    float* outp = (float*)d_out;

    // workspace layout (64.25 MB total, same footprint as prior rounds):
    //   [0, 48MB)        proj fp32 (4096x3072); later: gated (32MB) + wgT (8MB @ +40MB)
    //   [48MB, +256KB)   bias_rel (16x4095 fp32)
    //   [48.25MB, +16MB) wT (w_in^T split, 12MB) then attn-split output (16MB)
    char* ws = (char*)d_ws;
    float* proj              = (float*)ws;
    float* bias_rel          = (float*)(ws + 50331648);
    unsigned short* wT       = (unsigned short*)(ws + 50331648 + 262144);
    unsigned short* asplit   = wT;                                  // reuses wT after GEMM1
    unsigned short* wgT      = (unsigned short*)(ws + 41943040);    // dead proj space
    float* gated             = proj;

    tisa_bias_kernel<<<(H_ * REL_ + 255) / 256, 256, 0, stream>>>(amp, shp, off, bias_rel);
    convert_wT_kernel<<<dim3(D3_ / 64, D_ / 64), 256, 0, stream>>>(w_in, wT, D_, D3_);
    gemm_split_kernel<false><<<dim3(D3_ / 128, (B_ * S_) / 128), 256, 0, stream>>>(
        x, wT, nullptr, proj, B_ * S_, D3_, D_);
    attn_mfma_kernel<<<dim3(S_ / 64, H_, B_), 256, 0, stream>>>(proj, bias_rel, asplit);
    convert_wT_kernel<<<dim3(D2_ / 64, D_ / 64), 256, 0, stream>>>(w_gate, wgT, D_, D2_);
    gemm_split_kernel<true><<<dim3(D2_ / 128, (B_ * S_) / 128), 256, 0, stream>>>(
        asplit, wgT, b_gate, gated, B_ * S_, D2_, D_);
    gate_kernel<<<2048, 256, 0, stream>>>(gated, outp, (B_ * S_ * D_) / 4);
}

// Round 4
// 412.530 us; speedup vs baseline: 3.3461x; 1.0486x over previous
//
#include <hip/hip_runtime.h>
#include <math.h>

#define B_   2
#define S_   2048
#define D_   1024
#define H_   16
#define K_   21
#define HD_  64
#define D3_  3072
#define D2_  2048
#define REL_ 4095  // 2S-1

typedef __attribute__((ext_vector_type(8))) short bf16x8;
typedef __attribute__((ext_vector_type(8))) unsigned short u16x8;
typedef __attribute__((ext_vector_type(4))) float f32x4;

#define MFMA16(a, b, c) __builtin_amdgcn_mfma_f32_16x16x32_bf16((a), (b), (c), 0, 0, 0)

__device__ __forceinline__ unsigned short f2bf(float f) {
    union { float f; unsigned u; } v; v.f = f;
    return (unsigned short)((v.u + 0x7fffu + ((v.u >> 16) & 1u)) >> 16);
}
__device__ __forceinline__ float bf2f(unsigned short h) {
    union { unsigned u; float f; } v; v.u = ((unsigned)h) << 16;
    return v.f;
}
__device__ __forceinline__ unsigned packbf(float f) {
    unsigned short hi = f2bf(f);
    unsigned short lo = f2bf(f - bf2f(hi));
    return (unsigned)hi | ((unsigned)lo << 16);
}

// async global->LDS, 16B per lane; LDS dest = wave-uniform base + lane*16
__device__ __forceinline__ void gload16(const void* g, void* l) {
    __builtin_amdgcn_global_load_lds(
        (const __attribute__((address_space(1))) unsigned int*)g,
        (__attribute__((address_space(3))) unsigned int*)l, 16, 0, 0);
}

// unpack 8 packed u32 (hi|lo<<16) into hi/lo bf16x8 fragments
#define UNPACK8(v, ph, pl)                                                     \
    {                                                                          \
        _Pragma("unroll")                                                      \
        for (int _j = 0; _j < 4; ++_j) {                                       \
            ph.u[_j] = __builtin_amdgcn_perm(v[2*_j+1], v[2*_j], 0x05040100u); \
            pl.u[_j] = __builtin_amdgcn_perm(v[2*_j+1], v[2*_j], 0x07060302u); \
        }                                                                      \
    }

// ---------------- TISA relative-position bias table ----------------
__global__ void tisa_bias_kernel(const float* __restrict__ amp,
                                 const float* __restrict__ shp,
                                 const float* __restrict__ off,
                                 float* __restrict__ bias_rel) {
    int idx = blockIdx.x * blockDim.x + threadIdx.x;
    if (idx >= H_ * REL_) return;
    int h = idx / REL_;
    int r = idx - h * REL_;
    float rel = (float)(r - (S_ - 1));
    float acc = 0.f;
    #pragma unroll
    for (int k = 0; k < K_; ++k) {
        float d = rel - off[h * K_ + k];
        acc = fmaf(amp[h * K_ + k], expf(-fabsf(shp[h * K_ + k]) * d * d), acc);
    }
    bias_rel[idx] = acc;
}

// ---------------- weight transpose + bf16 split (chunk format) ----------------
// in: Kd x N fp32 row-major.  out: [N][Kd/32][64] ushort, chunk = hi[32] | lo[32].
__global__ __launch_bounds__(256) void convert_wT_kernel(
    const float* __restrict__ in, unsigned short* __restrict__ out, int Kd, int N)
{
    __shared__ float t[64][65];
    const int tid = threadIdx.x;
    const int k0 = blockIdx.y * 64;
    const int n0 = blockIdx.x * 64;
    {
        const int r  = tid >> 2;
        const int cq = (tid & 3) * 16;
        #pragma unroll
        for (int e = 0; e < 4; ++e) {
            float4 v = *(const float4*)&in[(size_t)(k0 + r) * N + n0 + cq + 4 * e];
            t[r][cq + 4 * e + 0] = v.x;
            t[r][cq + 4 * e + 1] = v.y;
            t[r][cq + 4 * e + 2] = v.z;
            t[r][cq + 4 * e + 3] = v.w;
        }
    }
    __syncthreads();
    {
        const int n  = tid >> 2;
        const int ks = (tid & 3) * 16;
        const int nkc = Kd >> 5;
        unsigned short hi[16], lo[16];
        #pragma unroll
        for (int i = 0; i < 16; ++i) {
            float v = t[ks + i][n];
            hi[i] = f2bf(v);
            lo[i] = f2bf(v - bf2f(hi[i]));
        }
        const int kg = k0 + ks;
        const int kc = kg >> 5;
        const int j0 = kg & 31;
        unsigned short* op = out + (size_t)(n0 + n) * (nkc * 64) + kc * 64;
        *(u16x8*)&op[j0]          = *(u16x8*)&hi[0];
        *(u16x8*)&op[j0 + 8]      = *(u16x8*)&hi[8];
        *(u16x8*)&op[32 + j0]     = *(u16x8*)&lo[0];
        *(u16x8*)&op[32 + j0 + 8] = *(u16x8*)&lo[8];
    }
}

// ---------------- in-place pack of proj K/V columns: fp32 -> u32(hi|lo<<16) ----
__global__ __launch_bounds__(256) void pack_kv_kernel(unsigned* proj32) {
    const int i = blockIdx.x * blockDim.x + threadIdx.x;  // uint4 index, 4096*512 total
    const int row = i >> 9;
    const int c4  = (i & 511) << 2;
    unsigned* p = proj32 + (size_t)row * D3_ + c4;
    float4 v = *(const float4*)p;
    uint4 o;
    o.x = packbf(v.x); o.y = packbf(v.y); o.z = packbf(v.z); o.w = packbf(v.w);
    *(uint4*)p = o;
}

// ---------------- bf16x3 split-precision MFMA GEMM ----------------
// C(Mx N fp32, ldc) = A * B [+bias].  B pre-converted chunks [N][K/32][hi32|lo32].
// A: fp32 row-major (ASPLIT=false, packed in-register during staging) or packed
// u32 hi|lo<<16 row-major with stride lda (ASPLIT=true, staged via gload16).
// 128x128 tile, 4 waves (2x2), BK=32; A-LDS packed u32, slot swizzle ^(row&7).
template<bool ASPLIT>
__global__ __launch_bounds__(256) void gemm_split_kernel(
    const void* Ap, const unsigned short* __restrict__ Bt,
    const float* __restrict__ bias, float* C,
    int N, int Kd, int lda, int ldc)
{
    __shared__ unsigned Al[128 * 32];        // packed u32, 16 KB
    __shared__ unsigned short Bl[128 * 64];  // chunk hi/lo, 16 KB
    const int tid  = threadIdx.x;
    const int w    = tid >> 6;
    const int lane = tid & 63;
    const int c    = lane & 15;
    const int g    = lane >> 4;
    const int m0   = blockIdx.y * 128;
    const int n0   = blockIdx.x * 128;
    const int wrow = (w >> 1) * 64;
    const int wcol = (w & 1) * 64;
    const int nkc  = Kd >> 5;

    f32x4 acc[4][4];
    #pragma unroll
    for (int i = 0; i < 4; ++i)
        #pragma unroll
        for (int j = 0; j < 4; ++j) acc[i][j] = (f32x4){0.f, 0.f, 0.f, 0.f};

    const int srowB  = w * 8 + (lane >> 3);
    const int sslotB = lane & 7;

    for (int kc = 0; kc < nkc; ++kc) {
        // ---- stage A ----
        if (ASPLIT) {
            #pragma unroll
            for (int i = 0; i < 4; ++i) {
                const int row = w * 32 + i * 8 + (lane >> 3);
                const int gs  = (lane & 7) ^ (row & 7);
                const unsigned* src = (const unsigned*)Ap
                    + (size_t)(m0 + row) * lda + kc * 32 + gs * 4;
                gload16(src, (char*)Al + w * 4096 + i * 1024);
            }
        } else {
            const int am  = tid >> 1;
            const int ah_ = tid & 1;
            const float* ap = (const float*)Ap + (size_t)(m0 + am) * lda + kc * 32 + ah_ * 16;
            float v[16];
            #pragma unroll
            for (int e = 0; e < 4; ++e)
                *(float4*)&v[4 * e] = *(const float4*)(ap + 4 * e);
            unsigned p[16];
            #pragma unroll
            for (int i = 0; i < 16; ++i) p[i] = packbf(v[i]);
            unsigned* rowp = Al + am * 32;
            #pragma unroll
            for (int q = 0; q < 4; ++q)
                *(uint4*)&rowp[((ah_ * 4 + q) ^ (am & 7)) * 4] = *(uint4*)&p[q * 4];
        }
        // ---- stage B ----
        #pragma unroll
        for (int i = 0; i < 4; ++i) {
            const int n = i * 32 + srowB;
            const unsigned short* src = Bt
                + ((size_t)(n0 + n) * nkc + kc) * 64 + ((sslotB ^ (n & 7)) << 3);
            gload16(src, (char*)Bl + i * 4096 + w * 1024);
        }
        __syncthreads();

        // ---- fragments + MFMA ----
        bf16x8 ah[4], al[4], bh[4], bl[4];
        #pragma unroll
        for (int f = 0; f < 4; ++f) {
            const int m = wrow + f * 16 + c;
            const unsigned* rp = Al + m * 32;
            uint4 a0 = *(const uint4*)&rp[((2 * g + 0) ^ (m & 7)) * 4];
            uint4 a1 = *(const uint4*)&rp[((2 * g + 1) ^ (m & 7)) * 4];
            unsigned v[8] = {a0.x, a0.y, a0.z, a0.w, a1.x, a1.y, a1.z, a1.w};
            union { unsigned u[4]; bf16x8 v; } ph, pl;
            UNPACK8(v, ph, pl);
            ah[f] = ph.v; al[f] = pl.v;
            const int n = wcol + f * 16 + c;
            const char* rq = (const char*)Bl + n * 128;
            bh[f] = *(const bf16x8*)(rq + (((g + 0) ^ (n & 7)) << 4));
            bl[f] = *(const bf16x8*)(rq + (((g + 4) ^ (n & 7)) << 4));
        }
        #pragma unroll
        for (int mf = 0; mf < 4; ++mf)
            #pragma unroll
            for (int nf = 0; nf < 4; ++nf) {
                acc[mf][nf] = MFMA16(ah[mf], bh[nf], acc[mf][nf]);
                acc[mf][nf] = MFMA16(al[mf], bh[nf], acc[mf][nf]);
                acc[mf][nf] = MFMA16(ah[mf], bl[nf], acc[mf][nf]);
            }
        __syncthreads();
    }

    // ---- epilogue ----
    float bs[4] = {0.f, 0.f, 0.f, 0.f};
    if (bias != nullptr) {
        #pragma unroll
        for (int nf = 0; nf < 4; ++nf) bs[nf] = bias[n0 + wcol + nf * 16 + c];
    }
    #pragma unroll
    for (int mf = 0; mf < 4; ++mf) {
        #pragma unroll
        for (int r = 0; r < 4; ++r) {
            const int row = m0 + wrow + mf * 16 + g * 4 + r;
            float* cp = &C[(size_t)row * ldc + n0 + wcol + c];
            #pragma unroll
            for (int nf = 0; nf < 4; ++nf)
                cp[nf * 16] = acc[mf][nf][r] + bs[nf];
        }
    }
}

// ---------------- MFMA flash attention, bf16x3, pre-packed K/V ----------------
// proj row (3072 elems, stride 12KB): cols [0,1024) = K packed u32,
// [1024,2048) = V packed u32, [2048,3072) = Q fp32 (overwritten with packed O).
__global__ __launch_bounds__(256) void attn_mfma_kernel(
    const float* projf, unsigned* proj32, const float* __restrict__ bias_rel)
{
    __shared__ unsigned Kl[64 * 64];   // [k][d] packed, slot-swizzled
    __shared__ unsigned Vt[64 * 64];   // [d][k] packed, slot-swizzled
    __shared__ unsigned P32[64 * 64];  // [q][k] packed
    __shared__ float bias_s[128];

    const int tid  = threadIdx.x;
    const int w    = tid >> 6;
    const int lane = tid & 63;
    const int c    = lane & 15;
    const int g    = lane >> 4;
    const int h    = blockIdx.y;
    const int b    = blockIdx.z;
    const int qbase = blockIdx.x * 64;
    const size_t rowbase = (size_t)b * S_;

    // Q fragments from fp32 Q-columns (read before any O writes)
    bf16x8 Qhi[2], Qlo[2];
    {
        const float* qp = projf + (rowbase + qbase + 16 * w + c) * D3_ + 2 * D_ + h * HD_;
        #pragma unroll
        for (int ck = 0; ck < 2; ++ck) {
            float q8[8];
            *(float4*)&q8[0] = *(const float4*)(qp + ck * 32 + g * 8);
            *(float4*)&q8[4] = *(const float4*)(qp + ck * 32 + g * 8 + 4);
            #pragma unroll
            for (int j = 0; j < 8; ++j) {
                unsigned short hi = f2bf(q8[j]);
                Qhi[ck][j] = (short)hi;
                Qlo[ck][j] = (short)f2bf(q8[j] - bf2f(hi));
            }
        }
    }

    f32x4 o_acc[4];
    #pragma unroll
    for (int n = 0; n < 4; ++n) o_acc[n] = (f32x4){0.f, 0.f, 0.f, 0.f};
    float m_run[4] = {-INFINITY, -INFINITY, -INFINITY, -INFINITY};
    float l_run[4] = {0.f, 0.f, 0.f, 0.f};

    for (int kt = 0; kt < S_ / 64; ++kt) {
        const int kbase = kt * 64;
        __syncthreads();  // previous tile's LDS reads complete

        // ---- stage K tile via global_load_lds (source-swizzled, linear LDS) ----
        #pragma unroll
        for (int i = 0; i < 4; ++i) {
            const int row = 16 * w + 4 * i + g;
            const int gs  = c ^ (row & 7);
            const unsigned* src = proj32 + (rowbase + kbase + row) * D3_ + h * HD_ + gs * 4;
            gload16(src, (char*)Kl + w * 4096 + i * 1024);
        }
        // ---- stage V tile transposed (packed regs -> swizzled ds_write_b32) ----
        {
            const int r  = tid >> 2;
            const int cq = (tid & 3) * 16;
            const unsigned* vp = proj32 + (rowbase + kbase + r) * D3_ + D_ + h * HD_ + cq;
            unsigned vv[16];
            #pragma unroll
            for (int e = 0; e < 4; ++e)
                *(uint4*)&vv[4 * e] = *(const uint4*)(vp + 4 * e);
            #pragma unroll
            for (int e = 0; e < 16; ++e) {
                const int d = cq + e;
                Vt[d * 64 + (((r >> 2) ^ (d & 7)) << 2) + (r & 3)] = vv[e];
            }
        }
        if (tid < 127)
            bias_s[tid] = bias_rel[h * REL_ + kbase - qbase + tid + 1984];
        __syncthreads();

        // ---- S = Q K^T (bf16x3) ----
        f32x4 sf[4];
        #pragma unroll
        for (int f = 0; f < 4; ++f) {
            f32x4 acc = (f32x4){0.f, 0.f, 0.f, 0.f};
            const int krow = f * 16 + c;
            const unsigned* kp = Kl + krow * 64;
            #pragma unroll
            for (int ck = 0; ck < 2; ++ck) {
                uint4 a0 = *(const uint4*)&kp[((ck * 8 + 2 * g + 0) ^ (krow & 7)) * 4];
                uint4 a1 = *(const uint4*)&kp[((ck * 8 + 2 * g + 1) ^ (krow & 7)) * 4];
                unsigned v[8] = {a0.x, a0.y, a0.z, a0.w, a1.x, a1.y, a1.z, a1.w};
                union { unsigned u[4]; bf16x8 v; } kh, klo;
                UNPACK8(v, kh, klo);
                acc = MFMA16(Qhi[ck], kh.v, acc);
                acc = MFMA16(Qlo[ck], kh.v, acc);
                acc = MFMA16(Qhi[ck], klo.v, acc);
            }
            sf[f] = acc;
        }

        // ---- scale + TISA bias ----
        #pragma unroll
        for (int f = 0; f < 4; ++f) {
            const int base = 16 * f + c + 63 - 16 * w - 4 * g;
            #pragma unroll
            for (int r = 0; r < 4; ++r)
                sf[f][r] = fmaf(sf[f][r], 0.125f, bias_s[base - r]);
        }

        // ---- online softmax (row = 4g+r, reduce over 16-lane group) ----
        #pragma unroll
        for (int r = 0; r < 4; ++r) {
            float mt = fmaxf(fmaxf(sf[0][r], sf[1][r]), fmaxf(sf[2][r], sf[3][r]));
            #pragma unroll
            for (int mask = 1; mask < 16; mask <<= 1)
                mt = fmaxf(mt, __shfl_xor(mt, mask));
            const float mn = fmaxf(m_run[r], mt);
            const float sc = __expf(m_run[r] - mn);
            float rs = 0.f;
            #pragma unroll
            for (int f = 0; f < 4; ++f) {
                const float p = __expf(sf[f][r] - mn);
                sf[f][r] = p;
                rs += p;
            }
            #pragma unroll
            for (int mask = 1; mask < 16; mask <<= 1)
                rs += __shfl_xor(rs, mask);
            l_run[r] = l_run[r] * sc + rs;
            m_run[r] = mn;
            #pragma unroll
            for (int n = 0; n < 4; ++n) o_acc[n][r] *= sc;
        }

        // ---- write P to LDS (packed, swizzled) ----
        #pragma unroll
        for (int f = 0; f < 4; ++f) {
            #pragma unroll
            for (int r = 0; r < 4; ++r) {
                const int m = 4 * g + r;
                P32[((16 * w + m) * 64 + 16 * f + c) ^ ((m & 7) << 2)] = packbf(sf[f][r]);
            }
        }
        __syncthreads();

        // ---- O += P V (bf16x3) ----
        #pragma unroll
        for (int ck = 0; ck < 2; ++ck) {
            const int base = (16 * w + c) * 64 + ck * 32 + g * 8;
            const int x = (c & 7) << 2;
            uint4 w0 = *(const uint4*)&P32[base ^ x];
            uint4 w1 = *(const uint4*)&P32[(base + 4) ^ x];
            unsigned pv[8] = {w0.x, w0.y, w0.z, w0.w, w1.x, w1.y, w1.z, w1.w};
            union { unsigned u[4]; bf16x8 v; } ph, pl;
            UNPACK8(pv, ph, pl);
            #pragma unroll
            for (int n = 0; n < 4; ++n) {
                const int d = 16 * n + c;
                const unsigned* vpr = Vt + d * 64;
                uint4 b0 = *(const uint4*)&vpr[((ck * 8 + 2 * g + 0) ^ (d & 7)) * 4];
                uint4 b1 = *(const uint4*)&vpr[((ck * 8 + 2 * g + 1) ^ (d & 7)) * 4];
                unsigned vb[8] = {b0.x, b0.y, b0.z, b0.w, b1.x, b1.y, b1.z, b1.w};
                union { unsigned u[4]; bf16x8 v; } vh, vl;
                UNPACK8(vb, vh, vl);
                o_acc[n] = MFMA16(ph.v, vh.v, o_acc[n]);
                o_acc[n] = MFMA16(pl.v, vh.v, o_acc[n]);
                o_acc[n] = MFMA16(ph.v, vl.v, o_acc[n]);
            }
        }
    }

    // ---- normalize + store packed O into proj Q-columns (for GEMM2 A) ----
    #pragma unroll
    for (int r = 0; r < 4; ++r) {
        const float inv = 1.f / l_run[r];
        unsigned* op = proj32 + (rowbase + qbase + 16 * w + 4 * g + r) * D3_ + 2 * D_ + h * HD_;
        #pragma unroll
        for (int n = 0; n < 4; ++n)
            op[16 * n + c] = packbf(o_acc[n][r] * inv);
    }
}

// ---------------- gating epilogue: out = a * sigmoid(g) ----------------
// gated lives in proj cols [0,2048) with row stride 3072
__global__ void gate_kernel(const float* __restrict__ gp,
                            float* __restrict__ outp, int n4)
{
    int idx = blockIdx.x * blockDim.x + threadIdx.x;
    const int stride = gridDim.x * blockDim.x;
    for (; idx < n4; idx += stride) {
        const int row = idx >> 8;
        const int c   = (idx & 255) * 4;
        const float4 a = *(const float4*)&gp[(size_t)row * D3_ + c];
        const float4 g = *(const float4*)&gp[(size_t)row * D3_ + D_ + c];
        float4 r;
        r.x = a.x / (1.f + __expf(-g.x));
        r.y = a.y / (1.f + __expf(-g.y));
        r.z = a.z / (1.f + __expf(-g.z));
        r.w = a.w / (1.f + __expf(-g.w));
        *(float4*)&outp[(size_t)idx * 4] = r;
    }
}

extern "C" void kernel_launch(void* const* d_in, const int* in_sizes, int n_in,
                              void* d_out, int out_size, void* d_ws, size_t ws_size,
                              hipStream_t stream) {
    const float* x      = (const float*)d_in[0];
    const float* w_in   = (const float*)d_in[1];
    const float* w_gate = (const float*)d_in[2];
    const float* b_gate = (const float*)d_in[3];
    const float* amp    = (const float*)d_in[4];
    const float* shp    = (const float*)d_in[5];
    const float* off    = (const float*)d_in[6];
    float* outp = (float*)d_out;

    // workspace (peak 60.5 MB):
    //   [0, 48M):      proj (4096 x 3072). fp32 from GEMM1; K/V cols packed u32 by
    //                  pack_kv; Q cols overwritten with packed O by attn; K/V cols
    //                  overwritten with fp32 gated by GEMM2.
    //   [48M, +256K):  bias_rel
    //   [48.25M,+12M): wT (w_in^T chunks); reused for wgT after GEMM1
    char* ws = (char*)d_ws;
    float*    proj   = (float*)ws;
    unsigned* proj32 = (unsigned*)ws;
    float*    bias_rel = (float*)(ws + 50331648);
    unsigned short* wT = (unsigned short*)(ws + 50331648 + 262144);

    tisa_bias_kernel<<<(H_ * REL_ + 255) / 256, 256, 0, stream>>>(amp, shp, off, bias_rel);
    convert_wT_kernel<<<dim3(D3_ / 64, D_ / 64), 256, 0, stream>>>(w_in, wT, D_, D3_);
    gemm_split_kernel<false><<<dim3(D3_ / 128, (B_ * S_) / 128), 256, 0, stream>>>(
        x, wT, nullptr, proj, D3_, D_, D_, D3_);
    pack_kv_kernel<<<8192, 256, 0, stream>>>(proj32);
    convert_wT_kernel<<<dim3(D2_ / 64, D_ / 64), 256, 0, stream>>>(w_gate, wT, D_, D2_);
    attn_mfma_kernel<<<dim3(S_ / 64, H_, B_), 256, 0, stream>>>(proj, proj32, bias_rel);
    gemm_split_kernel<true><<<dim3(D2_ / 128, (B_ * S_) / 128), 256, 0, stream>>>(
        proj32 + 2 * D_, wT, b_gate, proj, D2_, D_, D3_, D3_);
    gate_kernel<<<2048, 256, 0, stream>>>(proj, outp, (B_ * S_ * D_) / 4);
}

// Round 5
// 369.838 us; speedup vs baseline: 3.7324x; 1.1154x over previous
//
#include <hip/hip_runtime.h>
#include <math.h>

#define B_   2
#define S_   2048
#define D_   1024
#define H_   16
#define K_   21
#define HD_  64
#define D3_  3072
#define D2_  2048
#define REL_ 4095  // 2S-1

typedef __attribute__((ext_vector_type(8))) short bf16x8;
typedef __attribute__((ext_vector_type(8))) unsigned short u16x8;
typedef __attribute__((ext_vector_type(4))) float f32x4;

#define MFMA16(a, b, c) __builtin_amdgcn_mfma_f32_16x16x32_bf16((a), (b), (c), 0, 0, 0)

__device__ __forceinline__ unsigned short f2bf(float f) {
    union { float f; unsigned u; } v; v.f = f;
    return (unsigned short)((v.u + 0x7fffu + ((v.u >> 16) & 1u)) >> 16);
}
__device__ __forceinline__ float bf2f(unsigned short h) {
    union { unsigned u; float f; } v; v.u = ((unsigned)h) << 16;
    return v.f;
}
__device__ __forceinline__ unsigned packbf(float f) {
    unsigned short hi = f2bf(f);
    unsigned short lo = f2bf(f - bf2f(hi));
    return (unsigned)hi | ((unsigned)lo << 16);
}

// async global->LDS, 16B per lane; LDS dest = wave-uniform base + lane*16
__device__ __forceinline__ void gload16(const void* g, void* l) {
    __builtin_amdgcn_global_load_lds(
        (const __attribute__((address_space(1))) unsigned int*)g,
        (__attribute__((address_space(3))) unsigned int*)l, 16, 0, 0);
}

// unpack 8 packed u32 (hi|lo<<16) into hi/lo bf16x8 fragments
#define UNPACK8(v, ph, pl)                                                     \
    {                                                                          \
        _Pragma("unroll")                                                      \
        for (int _j = 0; _j < 4; ++_j) {                                       \
            ph.u[_j] = __builtin_amdgcn_perm(v[2*_j+1], v[2*_j], 0x05040100u); \
            pl.u[_j] = __builtin_amdgcn_perm(v[2*_j+1], v[2*_j], 0x07060302u); \
        }                                                                      \
    }

// ---------------- TISA relative-position bias table ----------------
__global__ void tisa_bias_kernel(const float* __restrict__ amp,
                                 const float* __restrict__ shp,
                                 const float* __restrict__ off,
                                 float* __restrict__ bias_rel) {
    int idx = blockIdx.x * blockDim.x + threadIdx.x;
    if (idx >= H_ * REL_) return;
    int h = idx / REL_;
    int r = idx - h * REL_;
    float rel = (float)(r - (S_ - 1));
    float acc = 0.f;
    #pragma unroll
    for (int k = 0; k < K_; ++k) {
        float d = rel - off[h * K_ + k];
        acc = fmaf(amp[h * K_ + k], expf(-fabsf(shp[h * K_ + k]) * d * d), acc);
    }
    bias_rel[idx] = acc;
}

// ---------------- weight transpose + bf16 split (chunk format) ----------------
// in: Kd x N fp32 row-major.  out: [N][Kd/32][64] ushort, chunk = hi[32] | lo[32].
__global__ __launch_bounds__(256) void convert_wT_kernel(
    const float* __restrict__ in, unsigned short* __restrict__ out, int Kd, int N)
{
    __shared__ float t[64][65];
    const int tid = threadIdx.x;
    const int k0 = blockIdx.y * 64;
    const int n0 = blockIdx.x * 64;
    {
        const int r  = tid >> 2;
        const int cq = (tid & 3) * 16;
        #pragma unroll
        for (int e = 0; e < 4; ++e) {
            float4 v = *(const float4*)&in[(size_t)(k0 + r) * N + n0 + cq + 4 * e];
            t[r][cq + 4 * e + 0] = v.x;
            t[r][cq + 4 * e + 1] = v.y;
            t[r][cq + 4 * e + 2] = v.z;
            t[r][cq + 4 * e + 3] = v.w;
        }
    }
    __syncthreads();
    {
        const int n  = tid >> 2;
        const int ks = (tid & 3) * 16;
        const int nkc = Kd >> 5;
        unsigned short hi[16], lo[16];
        #pragma unroll
        for (int i = 0; i < 16; ++i) {
            float v = t[ks + i][n];
            hi[i] = f2bf(v);
            lo[i] = f2bf(v - bf2f(hi[i]));
        }
        const int kg = k0 + ks;
        const int kc = kg >> 5;
        const int j0 = kg & 31;
        unsigned short* op = out + (size_t)(n0 + n) * (nkc * 64) + kc * 64;
        *(u16x8*)&op[j0]          = *(u16x8*)&hi[0];
        *(u16x8*)&op[j0 + 8]      = *(u16x8*)&hi[8];
        *(u16x8*)&op[32 + j0]     = *(u16x8*)&lo[0];
        *(u16x8*)&op[32 + j0 + 8] = *(u16x8*)&lo[8];
    }
}

// ---------------- V^T hi/lo planes: proj V cols -> vthi/vtlo [b][d][s] u16 ----
__global__ __launch_bounds__(256) void packV_kernel(
    const float* __restrict__ proj, unsigned short* __restrict__ vthi,
    unsigned short* __restrict__ vtlo)
{
    __shared__ float t[64][65];
    const int tid = threadIdx.x;
    const int d0 = blockIdx.x * 64;
    const int s0 = blockIdx.y * 64;
    const int b  = blockIdx.z;
    {
        const int r  = tid >> 2;
        const int cq = (tid & 3) * 16;
        const float* p = proj + ((size_t)(b * S_ + s0 + r)) * D3_ + D_ + d0 + cq;
        #pragma unroll
        for (int e = 0; e < 4; ++e) {
            float4 v = *(const float4*)(p + 4 * e);
            t[r][cq + 4 * e + 0] = v.x;
            t[r][cq + 4 * e + 1] = v.y;
            t[r][cq + 4 * e + 2] = v.z;
            t[r][cq + 4 * e + 3] = v.w;
        }
    }
    __syncthreads();
    {
        const int d  = tid >> 2;
        const int ks = (tid & 3) * 16;
        unsigned short hi[16], lo[16];
        #pragma unroll
        for (int i = 0; i < 16; ++i) {
            float v = t[ks + i][d];
            hi[i] = f2bf(v);
            lo[i] = f2bf(v - bf2f(hi[i]));
        }
        unsigned short* oh = vthi + ((size_t)(b * D_ + d0 + d)) * S_ + s0 + ks;
        unsigned short* ol = vtlo + ((size_t)(b * D_ + d0 + d)) * S_ + s0 + ks;
        *(u16x8*)oh       = *(u16x8*)&hi[0];
        *(u16x8*)(oh + 8) = *(u16x8*)&hi[8];
        *(u16x8*)ol       = *(u16x8*)&lo[0];
        *(u16x8*)(ol + 8) = *(u16x8*)&lo[8];
    }
}

// ---------------- K hi/lo planes written into proj's (dead) V columns ----------
// per row r: bytes [4096,6144) = Khi[1024] u16, [6144,8192) = Klo[1024] u16
__global__ __launch_bounds__(256) void packK_kernel(char* projB) {
    const int tid = threadIdx.x;
    const int row = blockIdx.x * 2 + (tid >> 7);
    const int c8  = (tid & 127) * 8;
    const float* src = (const float*)(projB + (size_t)row * 12288) + c8;
    float v[8];
    *(float4*)&v[0] = *(const float4*)src;
    *(float4*)&v[4] = *(const float4*)(src + 4);
    unsigned short hi[8], lo[8];
    #pragma unroll
    for (int i = 0; i < 8; ++i) {
        hi[i] = f2bf(v[i]);
        lo[i] = f2bf(v[i] - bf2f(hi[i]));
    }
    *(u16x8*)(projB + (size_t)row * 12288 + 4096 + (size_t)c8 * 2) = *(u16x8*)hi;
    *(u16x8*)(projB + (size_t)row * 12288 + 6144 + (size_t)c8 * 2) = *(u16x8*)lo;
}

// ---------------- bf16x3 split-precision MFMA GEMM ----------------
template<bool ASPLIT>
__global__ __launch_bounds__(256) void gemm_split_kernel(
    const void* Ap, const unsigned short* __restrict__ Bt,
    const float* __restrict__ bias, float* C,
    int N, int Kd, int lda, int ldc)
{
    __shared__ unsigned Al[128 * 32];        // packed u32, 16 KB
    __shared__ unsigned short Bl[128 * 64];  // chunk hi/lo, 16 KB
    const int tid  = threadIdx.x;
    const int w    = tid >> 6;
    const int lane = tid & 63;
    const int c    = lane & 15;
    const int g    = lane >> 4;
    const int m0   = blockIdx.y * 128;
    const int n0   = blockIdx.x * 128;
    const int wrow = (w >> 1) * 64;
    const int wcol = (w & 1) * 64;
    const int nkc  = Kd >> 5;

    f32x4 acc[4][4];
    #pragma unroll
    for (int i = 0; i < 4; ++i)
        #pragma unroll
        for (int j = 0; j < 4; ++j) acc[i][j] = (f32x4){0.f, 0.f, 0.f, 0.f};

    const int srowB  = w * 8 + (lane >> 3);
    const int sslotB = lane & 7;

    for (int kc = 0; kc < nkc; ++kc) {
        if (ASPLIT) {
            #pragma unroll
            for (int i = 0; i < 4; ++i) {
                const int row = w * 32 + i * 8 + (lane >> 3);
                const int gs  = (lane & 7) ^ (row & 7);
                const unsigned* src = (const unsigned*)Ap
                    + (size_t)(m0 + row) * lda + kc * 32 + gs * 4;
                gload16(src, (char*)Al + w * 4096 + i * 1024);
            }
        } else {
            const int am  = tid >> 1;
            const int ah_ = tid & 1;
            const float* ap = (const float*)Ap + (size_t)(m0 + am) * lda + kc * 32 + ah_ * 16;
            float v[16];
            #pragma unroll
            for (int e = 0; e < 4; ++e)
                *(float4*)&v[4 * e] = *(const float4*)(ap + 4 * e);
            unsigned p[16];
            #pragma unroll
            for (int i = 0; i < 16; ++i) p[i] = packbf(v[i]);
            unsigned* rowp = Al + am * 32;
            #pragma unroll
            for (int q = 0; q < 4; ++q)
                *(uint4*)&rowp[((ah_ * 4 + q) ^ (am & 7)) * 4] = *(uint4*)&p[q * 4];
        }
        #pragma unroll
        for (int i = 0; i < 4; ++i) {
            const int n = i * 32 + srowB;
            const unsigned short* src = Bt
                + ((size_t)(n0 + n) * nkc + kc) * 64 + ((sslotB ^ (n & 7)) << 3);
            gload16(src, (char*)Bl + i * 4096 + w * 1024);
        }
        __syncthreads();

        bf16x8 ah[4], al[4], bh[4], bl[4];
        #pragma unroll
        for (int f = 0; f < 4; ++f) {
            const int m = wrow + f * 16 + c;
            const unsigned* rp = Al + m * 32;
            uint4 a0 = *(const uint4*)&rp[((2 * g + 0) ^ (m & 7)) * 4];
            uint4 a1 = *(const uint4*)&rp[((2 * g + 1) ^ (m & 7)) * 4];
            unsigned v[8] = {a0.x, a0.y, a0.z, a0.w, a1.x, a1.y, a1.z, a1.w};
            union { unsigned u[4]; bf16x8 v; } ph, pl;
            UNPACK8(v, ph, pl);
            ah[f] = ph.v; al[f] = pl.v;
            const int n = wcol + f * 16 + c;
            const char* rq = (const char*)Bl + n * 128;
            bh[f] = *(const bf16x8*)(rq + (((g + 0) ^ (n & 7)) << 4));
            bl[f] = *(const bf16x8*)(rq + (((g + 4) ^ (n & 7)) << 4));
        }
        #pragma unroll
        for (int mf = 0; mf < 4; ++mf)
            #pragma unroll
            for (int nf = 0; nf < 4; ++nf) {
                acc[mf][nf] = MFMA16(ah[mf], bh[nf], acc[mf][nf]);
                acc[mf][nf] = MFMA16(al[mf], bh[nf], acc[mf][nf]);
                acc[mf][nf] = MFMA16(ah[mf], bl[nf], acc[mf][nf]);
            }
        __syncthreads();
    }

    float bs[4] = {0.f, 0.f, 0.f, 0.f};
    if (bias != nullptr) {
        #pragma unroll
        for (int nf = 0; nf < 4; ++nf) bs[nf] = bias[n0 + wcol + nf * 16 + c];
    }
    #pragma unroll
    for (int mf = 0; mf < 4; ++mf) {
        #pragma unroll
        for (int r = 0; r < 4; ++r) {
            const int row = m0 + wrow + mf * 16 + g * 4 + r;
            float* cp = &C[(size_t)row * ldc + n0 + wcol + c];
            #pragma unroll
            for (int nf = 0; nf < 4; ++nf)
                cp[nf * 16] = acc[mf][nf][r] + bs[nf];
        }
    }
}

// ---------------- MFMA flash attention: plane-format K/V, zero-perm frags ----
// K planes in proj rows (bytes [4096,6144)=Khi, [6144,8192)=Klo per row);
// V^T planes vtB (hi) / vtB+8MB (lo), layout [b][d][s] u16;
// Q fp32 in proj cols [2048,3072); O stored packed u32 over Q cols.
__global__ __launch_bounds__(256) void attn_mfma_kernel(
    const float* projf, unsigned* proj32, const char* projB,
    const char* vtB, const float* __restrict__ bias_rel)
{
    __shared__ unsigned short KHI[4096], KLO[4096], VHI[4096], VLO[4096];  // 8 KB each
    __shared__ unsigned P32[4096];                                         // 16 KB
    __shared__ float bias_s[128];

    const int tid  = threadIdx.x;
    const int w    = tid >> 6;
    const int lane = tid & 63;
    const int c    = lane & 15;
    const int g    = lane >> 4;
    const int h    = blockIdx.y;
    const int b    = blockIdx.z;
    const int qbase = blockIdx.x * 64;
    const size_t rowbase = (size_t)b * S_;

    // Q fragments from fp32 Q columns (retired before first barrier)
    bf16x8 Qhi[2], Qlo[2];
    {
        const float* qp = projf + (rowbase + qbase + 16 * w + c) * D3_ + 2 * D_ + h * HD_;
        #pragma unroll
        for (int ck = 0; ck < 2; ++ck) {
            float q8[8];
            *(float4*)&q8[0] = *(const float4*)(qp + ck * 32 + g * 8);
            *(float4*)&q8[4] = *(const float4*)(qp + ck * 32 + g * 8 + 4);
            #pragma unroll
            for (int j = 0; j < 8; ++j) {
                unsigned short hi = f2bf(q8[j]);
                Qhi[ck][j] = (short)hi;
                Qlo[ck][j] = (short)f2bf(q8[j] - bf2f(hi));
            }
        }
    }

    f32x4 o_acc[4];
    #pragma unroll
    for (int n = 0; n < 4; ++n) o_acc[n] = (f32x4){0.f, 0.f, 0.f, 0.f};
    float m_run[4] = {-INFINITY, -INFINITY, -INFINITY, -INFINITY};
    float l_run[4] = {0.f, 0.f, 0.f, 0.f};

    for (int kt = 0; kt < S_ / 64; ++kt) {
        const int kbase = kt * 64;
        __syncthreads();  // previous tile's LDS reads complete

        // ---- stage K hi/lo + V^T hi/lo via global_load_lds (src-swizzled) ----
        #pragma unroll
        for (int i = 0; i < 2; ++i) {
            const int row = w * 16 + i * 8 + (lane >> 3);
            const int gs  = (lane & 7) ^ (row & 7);
            const int dst = (w * 16 + i * 8) * 128;
            const char* ks = projB + (rowbase + kbase + row) * (size_t)12288
                           + 4096 + h * 128 + gs * 16;
            gload16(ks,        (char*)KHI + dst);
            gload16(ks + 2048, (char*)KLO + dst);
            const char* vs = vtB + ((size_t)(b * D_ + h * HD_ + row)) * 4096
                           + (size_t)kbase * 2 + gs * 16;
            gload16(vs,           (char*)VHI + dst);
            gload16(vs + 8388608, (char*)VLO + dst);
        }
        if (tid < 127)
            bias_s[tid] = bias_rel[h * REL_ + kbase - qbase + tid + 1984];
        __syncthreads();

        // ---- S = Q K^T (bf16x3), direct b128 fragment reads ----
        f32x4 sf[4];
        #pragma unroll
        for (int f = 0; f < 4; ++f) {
            f32x4 acc = (f32x4){0.f, 0.f, 0.f, 0.f};
            const int krow = f * 16 + c;
            const unsigned short* kbp = KHI + krow * 64;
            const unsigned short* klp = KLO + krow * 64;
            #pragma unroll
            for (int ck = 0; ck < 2; ++ck) {
                const int s = ((ck * 4 + g) ^ (krow & 7)) * 8;
                bf16x8 kh  = *(const bf16x8*)(kbp + s);
                bf16x8 kl8 = *(const bf16x8*)(klp + s);
                acc = MFMA16(Qhi[ck], kh, acc);
                acc = MFMA16(Qlo[ck], kh, acc);
                acc = MFMA16(Qhi[ck], kl8, acc);
            }
            sf[f] = acc;
        }

        // ---- scale + TISA bias ----
        #pragma unroll
        for (int f = 0; f < 4; ++f) {
            const int base = 16 * f + c + 63 - 16 * w - 4 * g;
            #pragma unroll
            for (int r = 0; r < 4; ++r)
                sf[f][r] = fmaf(sf[f][r], 0.125f, bias_s[base - r]);
        }

        // ---- online softmax (row = 4g+r, reduce over 16-lane group) ----
        #pragma unroll
        for (int r = 0; r < 4; ++r) {
            float mt = fmaxf(fmaxf(sf[0][r], sf[1][r]), fmaxf(sf[2][r], sf[3][r]));
            #pragma unroll
            for (int mask = 1; mask < 16; mask <<= 1)
                mt = fmaxf(mt, __shfl_xor(mt, mask));
            const float mn = fmaxf(m_run[r], mt);
            const float sc = __expf(m_run[r] - mn);
            float rs = 0.f;
            #pragma unroll
            for (int f = 0; f < 4; ++f) {
                const float p = __expf(sf[f][r] - mn);
                sf[f][r] = p;
                rs += p;
            }
            #pragma unroll
            for (int mask = 1; mask < 16; mask <<= 1)
                rs += __shfl_xor(rs, mask);
            l_run[r] = l_run[r] * sc + rs;
            m_run[r] = mn;
            #pragma unroll
            for (int n = 0; n < 4; ++n) o_acc[n][r] *= sc;
        }

        // ---- write P (packed u32, swizzled); wave-private rows -> lgkm wait ----
        #pragma unroll
        for (int f = 0; f < 4; ++f) {
            #pragma unroll
            for (int r = 0; r < 4; ++r) {
                const int m = 4 * g + r;
                P32[((16 * w + m) * 64 + 16 * f + c) ^ ((m & 7) << 2)] = packbf(sf[f][r]);
            }
        }
        asm volatile("s_waitcnt lgkmcnt(0)" ::: "memory");

        // ---- O += P V (bf16x3) ----
        #pragma unroll
        for (int ck = 0; ck < 2; ++ck) {
            const int base = (16 * w + c) * 64 + ck * 32 + g * 8;
            const int x = (c & 7) << 2;
            uint4 w0 = *(const uint4*)&P32[base ^ x];
            uint4 w1 = *(const uint4*)&P32[(base + 4) ^ x];
            unsigned pv[8] = {w0.x, w0.y, w0.z, w0.w, w1.x, w1.y, w1.z, w1.w};
            union { unsigned u[4]; bf16x8 v; } ph, pl;
            UNPACK8(pv, ph, pl);
            #pragma unroll
            for (int n = 0; n < 4; ++n) {
                const int d = 16 * n + c;
                const int s = ((ck * 4 + g) ^ (d & 7)) * 8;
                bf16x8 vh = *(const bf16x8*)(VHI + d * 64 + s);
                bf16x8 vl = *(const bf16x8*)(VLO + d * 64 + s);
                o_acc[n] = MFMA16(ph.v, vh, o_acc[n]);
                o_acc[n] = MFMA16(pl.v, vh, o_acc[n]);
                o_acc[n] = MFMA16(ph.v, vl, o_acc[n]);
            }
        }
    }

    // ---- normalize + store packed O into proj Q-columns (GEMM2 A) ----
    #pragma unroll
    for (int r = 0; r < 4; ++r) {
        const float inv = 1.f / l_run[r];
        unsigned* op = proj32 + (rowbase + qbase + 16 * w + 4 * g + r) * D3_ + 2 * D_ + h * HD_;
        #pragma unroll
        for (int n = 0; n < 4; ++n)
            op[16 * n + c] = packbf(o_acc[n][r] * inv);
    }
}

// ---------------- gating epilogue: out = a * sigmoid(g) ----------------
// gated lives in proj cols [0,2048) with row stride 3072
__global__ void gate_kernel(const float* __restrict__ gp,
                            float* __restrict__ outp, int n4)
{
    int idx = blockIdx.x * blockDim.x + threadIdx.x;
    const int stride = gridDim.x * blockDim.x;
    for (; idx < n4; idx += stride) {
        const int row = idx >> 8;
        const int c   = (idx & 255) * 4;
        const float4 a = *(const float4*)&gp[(size_t)row * D3_ + c];
        const float4 g = *(const float4*)&gp[(size_t)row * D3_ + D_ + c];
        float4 r;
        r.x = a.x / (1.f + __expf(-g.x));
        r.y = a.y / (1.f + __expf(-g.y));
        r.z = a.z / (1.f + __expf(-g.z));
        r.w = a.w / (1.f + __expf(-g.w));
        *(float4*)&outp[(size_t)idx * 4] = r;
    }
}

extern "C" void kernel_launch(void* const* d_in, const int* in_sizes, int n_in,
                              void* d_out, int out_size, void* d_ws, size_t ws_size,
                              hipStream_t stream) {
    const float* x      = (const float*)d_in[0];
    const float* w_in   = (const float*)d_in[1];
    const float* w_gate = (const float*)d_in[2];
    const float* b_gate = (const float*)d_in[3];
    const float* amp    = (const float*)d_in[4];
    const float* shp    = (const float*)d_in[5];
    const float* off    = (const float*)d_in[6];
    float* outp = (float*)d_out;

    // workspace (peak 64.25 MB, same as proven):
    //   [0,48M):      proj (4096x3072). GEMM1 writes fp32; packK writes K hi/lo
    //                 planes into V cols (bytes [4096,8192) per row); attn writes
    //                 packed O into Q cols; GEMM2 writes gated fp32 into cols
    //                 [0,2048); gate reads it.
    //   [48M,+256K):  bias_rel
    //   [48.25M,+16M): w_inT chunks (12M) -> V^T hi (8M) + lo (8M) after GEMM1
    //                 -> w_gateT chunks (8M) after attention
    char* ws = (char*)d_ws;
    float*    proj   = (float*)ws;
    unsigned* proj32 = (unsigned*)ws;
    float*    bias_rel = (float*)(ws + 50331648);
    unsigned short* wT = (unsigned short*)(ws + 50331648 + 262144);
    unsigned short* vthi = wT;
    unsigned short* vtlo = (unsigned short*)((char*)wT + 8388608);

    tisa_bias_kernel<<<(H_ * REL_ + 255) / 256, 256, 0, stream>>>(amp, shp, off, bias_rel);
    convert_wT_kernel<<<dim3(D3_ / 64, D_ / 64), 256, 0, stream>>>(w_in, wT, D_, D3_);
    gemm_split_kernel<false><<<dim3(D3_ / 128, (B_ * S_) / 128), 256, 0, stream>>>(
        x, wT, nullptr, proj, D3_, D_, D_, D3_);
    packV_kernel<<<dim3(D_ / 64, S_ / 64, B_), 256, 0, stream>>>(proj, vthi, vtlo);
    packK_kernel<<<(B_ * S_) / 2, 256, 0, stream>>>(ws);
    attn_mfma_kernel<<<dim3(S_ / 64, H_, B_), 256, 0, stream>>>(
        proj, proj32, ws, (const char*)vthi, bias_rel);
    convert_wT_kernel<<<dim3(D2_ / 64, D_ / 64), 256, 0, stream>>>(w_gate, wT, D_, D2_);
    gemm_split_kernel<true><<<dim3(D2_ / 128, (B_ * S_) / 128), 256, 0, stream>>>(
        proj32 + 2 * D_, wT, b_gate, proj, D2_, D_, D3_, D3_);
    gate_kernel<<<2048, 256, 0, stream>>>(proj, outp, (B_ * S_ * D_) / 4);
}